// Round 1
// baseline (2903.556 us; speedup 1.0000x reference)
//
#include <hip/hip_runtime.h>
#include <hip/hip_bf16.h>
#include <cstddef>

// ---------------- dims ----------------
#define S_DIM 512
#define B_DIM 256
#define PD 512
#define OD 256
#define DD 512
#define ID_DIM 1024
#define V_DIM 1000
#define EMB 64
#define IN0_PAD 80   // 1+EMB=65 padded to 80 for aligned float4 loads

// ---------------- helpers ----------------
__device__ __forceinline__ float sigmf(float x) { return 1.0f / (1.0f + expf(-x)); }

__device__ __forceinline__ float wred_max(float v) {
#pragma unroll
    for (int o = 32; o; o >>= 1) v = fmaxf(v, __shfl_xor(v, o));
    return v;
}
__device__ __forceinline__ float wred_sum(float v) {
#pragma unroll
    for (int o = 32; o; o >>= 1) v += __shfl_xor(v, o);
    return v;
}

// ---------------- build x (padded) ----------------
__global__ __launch_bounds__(128) void build_x_kernel(
    const float* __restrict__ p_ts, const int* __restrict__ p_cat,
    const float* __restrict__ emb, float* __restrict__ x)
{
    int b = blockIdx.x, t = threadIdx.x;
    if (t < IN0_PAD) {
        float val = 0.f;
        if (t == 0) val = p_ts[b];
        else if (t < 65) val = emb[(size_t)p_cat[b] * EMB + (t - 1)];
        x[(size_t)b * IN0_PAD + t] = val;
    }
}

// ---------------- pad W_ih0 [2048,65] -> [2048,80] ----------------
__global__ __launch_bounds__(256) void pad_w_kernel(
    const float* __restrict__ W, float* __restrict__ dst)
{
    int idx = blockIdx.x * 256 + threadIdx.x;
    if (idx < 2048 * IN0_PAD) {
        int r = idx / IN0_PAD, c = idx % IN0_PAD;
        dst[idx] = (c < 65) ? W[(size_t)r * 65 + c] : 0.f;
    }
}

// ---------------- generic GEMM: C = [C +] A @ W^T + b1 + b2, opt relu ----------------
// A [M,K] lda; W [N,K] rows with stride ldw; K % 16 == 0, lda/ldw % 4 == 0.
__global__ __launch_bounds__(256) void gemm_awt(
    const float* __restrict__ A, int lda,
    const float* __restrict__ W, int ldw,
    const float* __restrict__ bias1, const float* __restrict__ bias2,
    float* __restrict__ C, int ldc,
    int M, int N, int K, int accflag, int actrelu)
{
    __shared__ float As[16][68];
    __shared__ float Ws[16][68];
    const int tid = threadIdx.x;
    const int tx = tid & 15, ty = tid >> 4;
    const int bm = blockIdx.y << 6, bn = blockIdx.x << 6;
    const int lrow = tid >> 2;
    const int lk = (tid & 3) << 2;
    float acc[4][4] = {};
    for (int k0 = 0; k0 < K; k0 += 16) {
        float4 av = make_float4(0.f, 0.f, 0.f, 0.f);
        const int ar = bm + lrow;
        if (ar < M) av = *reinterpret_cast<const float4*>(A + (size_t)ar * lda + (k0 + lk));
        As[lk + 0][lrow] = av.x; As[lk + 1][lrow] = av.y;
        As[lk + 2][lrow] = av.z; As[lk + 3][lrow] = av.w;
        float4 wv = make_float4(0.f, 0.f, 0.f, 0.f);
        const int wr = bn + lrow;
        if (wr < N) wv = *reinterpret_cast<const float4*>(W + (size_t)wr * ldw + (k0 + lk));
        Ws[lk + 0][lrow] = wv.x; Ws[lk + 1][lrow] = wv.y;
        Ws[lk + 2][lrow] = wv.z; Ws[lk + 3][lrow] = wv.w;
        __syncthreads();
#pragma unroll
        for (int kk = 0; kk < 16; ++kk) {
            const float4 a = *reinterpret_cast<const float4*>(&As[kk][ty << 2]);
            const float4 w = *reinterpret_cast<const float4*>(&Ws[kk][tx << 2]);
            acc[0][0] += a.x * w.x; acc[0][1] += a.x * w.y; acc[0][2] += a.x * w.z; acc[0][3] += a.x * w.w;
            acc[1][0] += a.y * w.x; acc[1][1] += a.y * w.y; acc[1][2] += a.y * w.z; acc[1][3] += a.y * w.w;
            acc[2][0] += a.z * w.x; acc[2][1] += a.z * w.y; acc[2][2] += a.z * w.z; acc[2][3] += a.z * w.w;
            acc[3][0] += a.w * w.x; acc[3][1] += a.w * w.y; acc[3][2] += a.w * w.z; acc[3][3] += a.w * w.w;
        }
        __syncthreads();
    }
#pragma unroll
    for (int i = 0; i < 4; ++i) {
        const int r = bm + (ty << 2) + i;
        if (r >= M) continue;
#pragma unroll
        for (int j = 0; j < 4; ++j) {
            const int c = bn + (tx << 2) + j;
            if (c >= N) continue;
            float val = acc[i][j];
            if (bias1) val += bias1[c];
            if (bias2) val += bias2[c];
            if (accflag) val += C[(size_t)r * ldc + c];
            if (actrelu) val = fmaxf(val, 0.f);
            C[(size_t)r * ldc + c] = val;
        }
    }
}

// ---------------- fused attention score ----------------
// enc viewed as [M, E] (M = S*B, row m = (s,b)); Wenc rows n (n<512) stride ldw.
// score[b*Sdim + s] += sum_n tanh(enc_row . Wenc_n + decp[b,n]) * v[n]
__global__ __launch_bounds__(256) void attn_score(
    const float* __restrict__ enc,
    const float* __restrict__ Wenc, int ldw,
    const float* __restrict__ decp,
    const float* __restrict__ v,
    float* __restrict__ score,
    int M, int E, int Sdim)
{
    __shared__ float As[16][68];
    __shared__ float Ws[16][68];
    __shared__ float rowsum[64];
    const int tid = threadIdx.x;
    const int tx = tid & 15, ty = tid >> 4;
    const int bm = blockIdx.y << 6, bn = blockIdx.x << 6;
    const int lrow = tid >> 2;
    const int lk = (tid & 3) << 2;
    float acc[4][4] = {};
    for (int k0 = 0; k0 < E; k0 += 16) {
        const int ar = bm + lrow;
        float4 av = *reinterpret_cast<const float4*>(enc + (size_t)ar * E + (k0 + lk));
        As[lk + 0][lrow] = av.x; As[lk + 1][lrow] = av.y;
        As[lk + 2][lrow] = av.z; As[lk + 3][lrow] = av.w;
        const int wr = bn + lrow;  // < 512 always
        float4 wv = *reinterpret_cast<const float4*>(Wenc + (size_t)wr * ldw + (k0 + lk));
        Ws[lk + 0][lrow] = wv.x; Ws[lk + 1][lrow] = wv.y;
        Ws[lk + 2][lrow] = wv.z; Ws[lk + 3][lrow] = wv.w;
        __syncthreads();
#pragma unroll
        for (int kk = 0; kk < 16; ++kk) {
            const float4 a = *reinterpret_cast<const float4*>(&As[kk][ty << 2]);
            const float4 w = *reinterpret_cast<const float4*>(&Ws[kk][tx << 2]);
            acc[0][0] += a.x * w.x; acc[0][1] += a.x * w.y; acc[0][2] += a.x * w.z; acc[0][3] += a.x * w.w;
            acc[1][0] += a.y * w.x; acc[1][1] += a.y * w.y; acc[1][2] += a.y * w.z; acc[1][3] += a.y * w.w;
            acc[2][0] += a.z * w.x; acc[2][1] += a.z * w.y; acc[2][2] += a.z * w.z; acc[2][3] += a.z * w.w;
            acc[3][0] += a.w * w.x; acc[3][1] += a.w * w.y; acc[3][2] += a.w * w.z; acc[3][3] += a.w * w.w;
        }
        __syncthreads();
    }
    if (tid < 64) rowsum[tid] = 0.f;
    __syncthreads();
    float part[4] = {0.f, 0.f, 0.f, 0.f};
#pragma unroll
    for (int i = 0; i < 4; ++i) {
        const int r = bm + (ty << 2) + i;
        const int b = r & (B_DIM - 1);
#pragma unroll
        for (int j = 0; j < 4; ++j) {
            const int n = bn + (tx << 2) + j;
            float e = tanhf(acc[i][j] + decp[(b << 9) + n]);
            part[i] += e * v[n];
        }
    }
#pragma unroll
    for (int i = 0; i < 4; ++i) atomicAdd(&rowsum[(ty << 2) + i], part[i]);
    __syncthreads();
    if (tid < 64) {
        const int r = bm + tid;
        if (r < M)
            atomicAdd(&score[(size_t)(r & (B_DIM - 1)) * Sdim + (r >> 8)], rowsum[tid]);
    }
}

// ---------------- softmax rows in place: x [B, Sdim] ----------------
__global__ __launch_bounds__(256) void softmax_rows(float* __restrict__ x, int Sdim)
{
    const int b = blockIdx.x, tid = threadIdx.x;
    const int lane = tid & 63, wid = tid >> 6;
    float* row = x + (size_t)b * Sdim;
    __shared__ float tmp[4];
    float m = -3.4e38f;
    for (int s = tid; s < Sdim; s += 256) m = fmaxf(m, row[s]);
    m = wred_max(m);
    if (lane == 0) tmp[wid] = m;
    __syncthreads();
    m = fmaxf(fmaxf(tmp[0], tmp[1]), fmaxf(tmp[2], tmp[3]));
    __syncthreads();
    float sum = 0.f;
    for (int s = tid; s < Sdim; s += 256) { float e = expf(row[s] - m); row[s] = e; sum += e; }
    sum = wred_sum(sum);
    if (lane == 0) tmp[wid] = sum;
    __syncthreads();
    sum = tmp[0] + tmp[1] + tmp[2] + tmp[3];
    const float inv = 1.0f / sum;
    for (int s = tid; s < Sdim; s += 256) row[s] *= inv;
}

// ---------------- weighted context: out[b,e] = sum_s w[b,s] enc[s,b,e] ----------------
__global__ __launch_bounds__(256) void ctx_kernel(
    const float* __restrict__ w, const float* __restrict__ enc,
    float* __restrict__ out, int Sdim, int E)
{
    const int b = blockIdx.x;
    const int e = blockIdx.y * 256 + threadIdx.x;
    if (e >= E) return;
    const float* wr = w + (size_t)b * Sdim;
    float acc = 0.f;
#pragma unroll 4
    for (int s = 0; s < Sdim; ++s)
        acc += wr[s] * enc[((size_t)s * B_DIM + b) * E + e];
    out[(size_t)b * E + e] = acc;
}

// ---------------- LSTM pointwise ----------------
__global__ __launch_bounds__(256) void lstm_pw(
    const float* __restrict__ g, const float* __restrict__ cprev,
    float* __restrict__ h_out, float* __restrict__ c_out, float* __restrict__ h_copy)
{
    const int idx = blockIdx.x * 256 + threadIdx.x;  // over B*512
    const int b = idx >> 9, d = idx & 511;
    const float* gr = g + (size_t)b * 2048;
    const float ig = sigmf(gr[d]);
    const float fg = sigmf(gr[512 + d]);
    const float gg = tanhf(gr[1024 + d]);
    const float og = sigmf(gr[1536 + d]);
    const float c2 = fg * cprev[idx] + ig * gg;
    const float h2 = og * tanhf(c2);
    h_out[idx] = h2; c_out[idx] = c2; h_copy[idx] = h2;
}

// ---------------- ts head ----------------
__global__ __launch_bounds__(64) void ts_kernel(
    const float* __restrict__ h2, const float* __restrict__ tgW,
    const float* __restrict__ tgb, float* __restrict__ out)
{
    const int b = blockIdx.x, t = threadIdx.x;
    float s = 0.f;
    for (int d = t; d < 512; d += 64) s += h2[(size_t)b * 512 + d] * tgW[d];
    s = wred_sum(s);
    if (t == 0) out[b] = fmaxf(s + tgb[0], 0.f);
}

// ---------------- log softmax rows: in [B,V] -> out [B,V] ----------------
__global__ __launch_bounds__(256) void log_softmax_rows(
    const float* __restrict__ in, float* __restrict__ out, int V)
{
    const int b = blockIdx.x, tid = threadIdx.x;
    const int lane = tid & 63, wid = tid >> 6;
    const float* row = in + (size_t)b * V;
    float* orow = out + (size_t)b * V;
    __shared__ float tmp[4];
    float m = -3.4e38f;
    for (int s = tid; s < V; s += 256) m = fmaxf(m, row[s]);
    m = wred_max(m);
    if (lane == 0) tmp[wid] = m;
    __syncthreads();
    m = fmaxf(fmaxf(tmp[0], tmp[1]), fmaxf(tmp[2], tmp[3]));
    __syncthreads();
    float sum = 0.f;
    for (int s = tid; s < V; s += 256) sum += expf(row[s] - m);
    sum = wred_sum(sum);
    if (lane == 0) tmp[wid] = sum;
    __syncthreads();
    sum = tmp[0] + tmp[1] + tmp[2] + tmp[3];
    const float lse = m + logf(sum);
    for (int s = tid; s < V; s += 256) orow[s] = row[s] - lse;
}

// ---------------- host ----------------
extern "C" void kernel_launch(void* const* d_in, const int* in_sizes, int n_in,
                              void* d_out, int out_size, void* d_ws, size_t ws_size,
                              hipStream_t stream)
{
    const float* p_ts   = (const float*)d_in[0];
    const int*   p_cat  = (const int*)d_in[1];
    const float* p_hn   = (const float*)d_in[2];
    const float* p_hc   = (const float*)d_in[3];
    const float* p_enc  = (const float*)d_in[4];
    const float* a_enc  = (const float*)d_in[5];
    const float* i_enc  = (const float*)d_in[6];
    const float* emb    = (const float*)d_in[7];
    const float* W_ih0  = (const float*)d_in[8];
    const float* W_hh0  = (const float*)d_in[9];
    const float* b_ih0  = (const float*)d_in[10];
    const float* b_hh0  = (const float*)d_in[11];
    const float* W_ih1  = (const float*)d_in[12];
    const float* W_hh1  = (const float*)d_in[13];
    const float* b_ih1  = (const float*)d_in[14];
    const float* b_hh1  = (const float*)d_in[15];
    const float* pW = (const float*)d_in[16]; const float* pb = (const float*)d_in[17]; const float* pv = (const float*)d_in[18];
    const float* aW = (const float*)d_in[19]; const float* ab = (const float*)d_in[20]; const float* av = (const float*)d_in[21];
    const float* iW = (const float*)d_in[22]; const float* ib = (const float*)d_in[23]; const float* iv = (const float*)d_in[24];
    const float* cW = (const float*)d_in[25]; const float* cb = (const float*)d_in[26]; const float* cv = (const float*)d_in[27];
    const float* p2o_W = (const float*)d_in[28]; const float* p2o_b = (const float*)d_in[29];
    const float* o2p_W = (const float*)d_in[30]; const float* o2p_b = (const float*)d_in[31];
    const float* out1_W = (const float*)d_in[32]; const float* out1_b = (const float*)d_in[33];
    const float* out2_W = (const float*)d_in[34]; const float* out2_b = (const float*)d_in[35];
    const float* mg_W = (const float*)d_in[36]; const float* mg_b = (const float*)d_in[37];
    const float* tg_W = (const float*)d_in[38]; const float* tg_b = (const float*)d_in[39];

    float* out = (float*)d_out;
    float* ws  = (float*)d_ws;

    // ---- output offsets (floats) ----
    float* out_ts  = out;                      // 256
    float* out_cat = out + 256;                // 256*1000
    float* out_hn0 = out + 256256;             // 131072
    float* out_hn1 = out + 256256 + 131072;
    float* out_hc0 = out + 518400;
    float* out_hc1 = out + 518400 + 131072;

    // ---- workspace layout (floats) ----
    size_t off = 0;
    float* x_pad   = ws + off; off += (size_t)B_DIM * IN0_PAD;      // 20480
    float* wpad    = ws + off; off += (size_t)2048 * IN0_PAD;       // 163840
    float* g_buf   = ws + off; off += (size_t)B_DIM * 2048;         // 524288
    float* h0_ws   = ws + off; off += (size_t)B_DIM * DD;
    float* h1_ws   = ws + off; off += (size_t)B_DIM * DD;
    float* decp_p  = ws + off; off += (size_t)B_DIM * DD;
    float* decp_a  = ws + off; off += (size_t)B_DIM * DD;
    float* decp_i  = ws + off; off += (size_t)B_DIM * DD;
    float* decp_c  = ws + off; off += (size_t)B_DIM * DD;
    float* score_p = ws + off; off += (size_t)B_DIM * S_DIM;
    float* score_a = ws + off; off += (size_t)B_DIM * S_DIM;
    float* score_i = ws + off; off += (size_t)B_DIM * S_DIM;
    float* score_c = ws + off; off += 1024;                          // B*3 rounded up
    float* p_ctx   = ws + off; off += (size_t)B_DIM * PD;
    float* combined= ws + off; off += (size_t)3 * B_DIM * OD;
    float* ctx_c   = ws + off; off += (size_t)B_DIM * OD;
    float* context = ws + off; off += (size_t)B_DIM * DD;
    float* h_big   = ws + off; off += (size_t)B_DIM * ID_DIM;
    float* h2_buf  = ws + off; off += (size_t)B_DIM * DD;
    float* logits  = ws + off; off += (size_t)B_DIM * V_DIM;
    (void)ws_size; (void)n_in; (void)in_sizes; (void)out_size;

    auto gemm = [&](const float* A, int lda, const float* W, int ldw,
                    const float* b1, const float* b2, float* C, int ldc,
                    int M, int N, int K, int acc, int relu) {
        dim3 grid((N + 63) / 64, (M + 63) / 64);
        gemm_awt<<<grid, 256, 0, stream>>>(A, lda, W, ldw, b1, b2, C, ldc, M, N, K, acc, relu);
    };

    // zero the score buffers (attn_score accumulates via atomics)
    hipMemsetAsync(score_p, 0, (size_t)(3 * B_DIM * S_DIM + 1024) * sizeof(float), stream);

    // 1) build x, pad W_ih0
    build_x_kernel<<<B_DIM, 128, 0, stream>>>(p_ts, p_cat, emb, x_pad);
    pad_w_kernel<<<(2048 * IN0_PAD + 255) / 256, 256, 0, stream>>>(W_ih0, wpad);

    // 2) LSTM layer 0
    gemm(x_pad, IN0_PAD, wpad, IN0_PAD, b_ih0, b_hh0, g_buf, 2048, B_DIM, 2048, IN0_PAD, 0, 0);
    gemm(p_hn, DD, W_hh0, DD, nullptr, nullptr, g_buf, 2048, B_DIM, 2048, DD, 1, 0);
    lstm_pw<<<(B_DIM * DD) / 256, 256, 0, stream>>>(g_buf, p_hc, out_hn0, out_hc0, h0_ws);

    // 3) LSTM layer 1
    gemm(h0_ws, DD, W_ih1, DD, b_ih1, b_hh1, g_buf, 2048, B_DIM, 2048, DD, 0, 0);
    gemm(p_hn + (size_t)B_DIM * DD, DD, W_hh1, DD, nullptr, nullptr, g_buf, 2048, B_DIM, 2048, DD, 1, 0);
    lstm_pw<<<(B_DIM * DD) / 256, 256, 0, stream>>>(g_buf, p_hc + (size_t)B_DIM * DD, out_hn1, out_hc1, h1_ws);

    // 4) dec projections: decp_x = h1 @ W[:, :512]^T + bias
    gemm(h1_ws, DD, pW, PD + DD, pb, nullptr, decp_p, DD, B_DIM, DD, DD, 0, 0);
    gemm(h1_ws, DD, aW, OD + DD, ab, nullptr, decp_a, DD, B_DIM, DD, DD, 0, 0);
    gemm(h1_ws, DD, iW, OD + DD, ib, nullptr, decp_i, DD, B_DIM, DD, DD, 0, 0);
    gemm(h1_ws, DD, cW, OD + DD, cb, nullptr, decp_c, DD, B_DIM, DD, DD, 0, 0);

    // 5) p attention
    {
        dim3 grid(8, (S_DIM * B_DIM) / 64);
        attn_score<<<grid, 256, 0, stream>>>(p_enc, pW + PD /*cols D..*/ , PD + DD,
                                             decp_p, pv, score_p, S_DIM * B_DIM, PD, S_DIM);
        // NOTE: Wenc for p is pW[:, DD:] i.e. offset DD=512; PD==DD==512 so pW+512 is correct.
        softmax_rows<<<B_DIM, 256, 0, stream>>>(score_p, S_DIM);
        dim3 cg(B_DIM, PD / 256);
        ctx_kernel<<<cg, 256, 0, stream>>>(score_p, p_enc, p_ctx, S_DIM, PD);
    }
    // 6) a attention -> combined slot 1
    {
        dim3 grid(8, (S_DIM * B_DIM) / 64);
        attn_score<<<grid, 256, 0, stream>>>(a_enc, aW + DD, OD + DD,
                                             decp_a, av, score_a, S_DIM * B_DIM, OD, S_DIM);
        softmax_rows<<<B_DIM, 256, 0, stream>>>(score_a, S_DIM);
        dim3 cg(B_DIM, 1);
        ctx_kernel<<<cg, 256, 0, stream>>>(score_a, a_enc, combined + (size_t)B_DIM * OD, S_DIM, OD);
    }
    // 7) i attention -> combined slot 2
    {
        dim3 grid(8, (S_DIM * B_DIM) / 64);
        attn_score<<<grid, 256, 0, stream>>>(i_enc, iW + DD, OD + DD,
                                             decp_i, iv, score_i, S_DIM * B_DIM, OD, S_DIM);
        softmax_rows<<<B_DIM, 256, 0, stream>>>(score_i, S_DIM);
        dim3 cg(B_DIM, 1);
        ctx_kernel<<<cg, 256, 0, stream>>>(score_i, i_enc, combined + (size_t)2 * B_DIM * OD, S_DIM, OD);
    }
    // 8) combined slot 0 = relu(p_ctx @ p2o_W^T + p2o_b)
    gemm(p_ctx, PD, p2o_W, PD, p2o_b, nullptr, combined, OD, B_DIM, OD, PD, 0, 1);

    // 9) combiner attention over S'=3
    {
        dim3 grid(8, (3 * B_DIM) / 64);
        attn_score<<<grid, 256, 0, stream>>>(combined, cW + DD, OD + DD,
                                             decp_c, cv, score_c, 3 * B_DIM, OD, 3);
        softmax_rows<<<B_DIM, 256, 0, stream>>>(score_c, 3);
        dim3 cg(B_DIM, 1);
        ctx_kernel<<<cg, 256, 0, stream>>>(score_c, combined, ctx_c, 3, OD);
    }

    // 10) context = relu(ctx_c @ o2p_W^T + o2p_b)
    gemm(ctx_c, OD, o2p_W, OD, o2p_b, nullptr, context, DD, B_DIM, DD, OD, 0, 1);

    // 11) h = relu([context, h1] @ out1_W^T + out1_b)  (two-phase accumulate)
    gemm(context, DD, out1_W, 2 * DD, out1_b, nullptr, h_big, ID_DIM, B_DIM, ID_DIM, DD, 0, 0);
    gemm(h1_ws, DD, out1_W + DD, 2 * DD, nullptr, nullptr, h_big, ID_DIM, B_DIM, ID_DIM, DD, 1, 1);

    // 12) h2 = relu(h @ out2_W^T + out2_b)
    gemm(h_big, ID_DIM, out2_W, ID_DIM, out2_b, nullptr, h2_buf, DD, B_DIM, DD, ID_DIM, 0, 1);

    // 13) ts = relu(h2 @ tg_W^T + tg_b)
    ts_kernel<<<B_DIM, 64, 0, stream>>>(h2_buf, tg_W, tg_b, out_ts);

    // 14) cat = log_softmax(h2 @ mg_W^T + mg_b)
    gemm(h2_buf, DD, mg_W, DD, mg_b, nullptr, logits, V_DIM, B_DIM, V_DIM, DD, 0, 0);
    log_softmax_rows<<<B_DIM, 256, 0, stream>>>(logits, out_cat, V_DIM);
}

// Round 2
// 1263.573 us; speedup vs baseline: 2.2979x; 2.2979x over previous
//
#include <hip/hip_runtime.h>
#include <hip/hip_bf16.h>
#include <cstddef>

// ---------------- dims ----------------
#define S_DIM 512
#define B_DIM 256
#define PD 512
#define OD 256
#define DD 512
#define ID_DIM 1024
#define V_DIM 1000
#define EMB 64
#define IN0_PAD 80   // 1+EMB=65 padded to 80 for aligned float4 loads

typedef short short8 __attribute__((ext_vector_type(8)));
typedef float f32x4 __attribute__((ext_vector_type(4)));
typedef unsigned short us4 __attribute__((ext_vector_type(4)));

// ---------------- helpers ----------------
__device__ __forceinline__ float sigmf(float x) { return 1.0f / (1.0f + expf(-x)); }

__device__ __forceinline__ unsigned short f2bfu(float f) {
    __hip_bfloat16 h = __float2bfloat16(f);
    return *reinterpret_cast<unsigned short*>(&h);
}

__device__ __forceinline__ float wred_max(float v) {
#pragma unroll
    for (int o = 32; o; o >>= 1) v = fmaxf(v, __shfl_xor(v, o));
    return v;
}
__device__ __forceinline__ float wred_sum(float v) {
#pragma unroll
    for (int o = 32; o; o >>= 1) v += __shfl_xor(v, o);
    return v;
}

// ---------------- build x (padded) ----------------
__global__ __launch_bounds__(128) void build_x_kernel(
    const float* __restrict__ p_ts, const int* __restrict__ p_cat,
    const float* __restrict__ emb, float* __restrict__ x)
{
    int b = blockIdx.x, t = threadIdx.x;
    if (t < IN0_PAD) {
        float val = 0.f;
        if (t == 0) val = p_ts[b];
        else if (t < 65) val = emb[(size_t)p_cat[b] * EMB + (t - 1)];
        x[(size_t)b * IN0_PAD + t] = val;
    }
}

// ---------------- pad W_ih0 [2048,65] -> [2048,80] ----------------
__global__ __launch_bounds__(256) void pad_w_kernel(
    const float* __restrict__ W, float* __restrict__ dst)
{
    int idx = blockIdx.x * 256 + threadIdx.x;
    if (idx < 2048 * IN0_PAD) {
        int r = idx / IN0_PAD, c = idx % IN0_PAD;
        dst[idx] = (c < 65) ? W[(size_t)r * 65 + c] : 0.f;
    }
}

// ---------------- convert W slice [nrows, ncols] from src[:, col0:col0+ncols] to bf16 ----------------
__global__ __launch_bounds__(256) void convert_w(
    const float* __restrict__ src, int ldsrc, int col0, int nrows, int ncols,
    unsigned short* __restrict__ dst)
{
    int idx = blockIdx.x * 256 + threadIdx.x;
    if (idx < nrows * ncols) {
        int r = idx / ncols, c = idx - r * ncols;
        dst[idx] = f2bfu(src[(size_t)r * ldsrc + col0 + c]);
    }
}

// ---------------- generic GEMM: C = [C +] A @ W^T + b1 + b2, opt relu ----------------
__global__ __launch_bounds__(256) void gemm_awt(
    const float* __restrict__ A, int lda,
    const float* __restrict__ W, int ldw,
    const float* __restrict__ bias1, const float* __restrict__ bias2,
    float* __restrict__ C, int ldc,
    int M, int N, int K, int accflag, int actrelu)
{
    __shared__ float As[16][68];
    __shared__ float Ws[16][68];
    const int tid = threadIdx.x;
    const int tx = tid & 15, ty = tid >> 4;
    const int bm = blockIdx.y << 6, bn = blockIdx.x << 6;
    const int lrow = tid >> 2;
    const int lk = (tid & 3) << 2;
    float acc[4][4] = {};
    for (int k0 = 0; k0 < K; k0 += 16) {
        float4 av = make_float4(0.f, 0.f, 0.f, 0.f);
        const int ar = bm + lrow;
        if (ar < M) av = *reinterpret_cast<const float4*>(A + (size_t)ar * lda + (k0 + lk));
        As[lk + 0][lrow] = av.x; As[lk + 1][lrow] = av.y;
        As[lk + 2][lrow] = av.z; As[lk + 3][lrow] = av.w;
        float4 wv = make_float4(0.f, 0.f, 0.f, 0.f);
        const int wr = bn + lrow;
        if (wr < N) wv = *reinterpret_cast<const float4*>(W + (size_t)wr * ldw + (k0 + lk));
        Ws[lk + 0][lrow] = wv.x; Ws[lk + 1][lrow] = wv.y;
        Ws[lk + 2][lrow] = wv.z; Ws[lk + 3][lrow] = wv.w;
        __syncthreads();
#pragma unroll
        for (int kk = 0; kk < 16; ++kk) {
            const float4 a = *reinterpret_cast<const float4*>(&As[kk][ty << 2]);
            const float4 w = *reinterpret_cast<const float4*>(&Ws[kk][tx << 2]);
            acc[0][0] += a.x * w.x; acc[0][1] += a.x * w.y; acc[0][2] += a.x * w.z; acc[0][3] += a.x * w.w;
            acc[1][0] += a.y * w.x; acc[1][1] += a.y * w.y; acc[1][2] += a.y * w.z; acc[1][3] += a.y * w.w;
            acc[2][0] += a.z * w.x; acc[2][1] += a.z * w.y; acc[2][2] += a.z * w.z; acc[2][3] += a.z * w.w;
            acc[3][0] += a.w * w.x; acc[3][1] += a.w * w.y; acc[3][2] += a.w * w.z; acc[3][3] += a.w * w.w;
        }
        __syncthreads();
    }
#pragma unroll
    for (int i = 0; i < 4; ++i) {
        const int r = bm + (ty << 2) + i;
        if (r >= M) continue;
#pragma unroll
        for (int j = 0; j < 4; ++j) {
            const int c = bn + (tx << 2) + j;
            if (c >= N) continue;
            float val = acc[i][j];
            if (bias1) val += bias1[c];
            if (bias2) val += bias2[c];
            if (accflag) val += C[(size_t)r * ldc + c];
            if (actrelu) val = fmaxf(val, 0.f);
            C[(size_t)r * ldc + c] = val;
        }
    }
}

// ---------------- MFMA fused attention score ----------------
// enc [M, E] f32 (M = S*B, row m = s*B + b); Wb [512, E] bf16 (enc-half of attn W).
// score[b*Sdim + s] = sum_n tanh( enc_row(m) . Wb_n + decp[b,n] ) * v[n],  n = 0..511
// Block: 64 enc rows x all 512 n. 8 waves; wave w owns n in [64w, 64w+64).
// Orientation: A-operand = Wb (rows n), B-operand = enc (cols m).
__global__ __launch_bounds__(512, 4) void attn_score_mfma(
    const float* __restrict__ enc,
    const unsigned short* __restrict__ Wb,
    const float* __restrict__ decp,
    const float* __restrict__ v,
    float* __restrict__ score,
    int E, int Sdim)
{
    __shared__ alignas(16) unsigned short Al[2][64][40];  // stride 40 elems = 80B: bank-uniform b128 reads
    __shared__ float red[64][9];
    const int tid = threadIdx.x;
    const int w = tid >> 6, l = tid & 63;
    const int m0 = blockIdx.x << 6;
    const int nsteps = E >> 5;

    const int srow = tid >> 3;           // staging: row 0..63
    const int scol = (tid & 7) << 2;     // staging: k offset 0..28
    const float* srcp = enc + (size_t)(m0 + srow) * E + scol;

    // prologue: stage k-step 0
    {
        float4 sv = *reinterpret_cast<const float4*>(srcp);
        us4 pk = { f2bfu(sv.x), f2bfu(sv.y), f2bfu(sv.z), f2bfu(sv.w) };
        *reinterpret_cast<us4*>(&Al[0][srow][scol]) = pk;
    }
    __syncthreads();

    f32x4 acc[4][4] = {};
    const int lk = (l >> 4) << 3;        // k sub-offset within 32: 0,8,16,24
    const unsigned short* wbase = Wb + (size_t)((w << 6) + (l & 15)) * E + lk;

    int buf = 0;
    for (int ks = 0; ks < nsteps; ++ks) {
        float4 nv;
        const bool more = (ks + 1) < nsteps;
        if (more) nv = *reinterpret_cast<const float4*>(srcp + ((ks + 1) << 5));

        short8 bfr[4];
#pragma unroll
        for (int ni = 0; ni < 4; ++ni)
            bfr[ni] = *reinterpret_cast<const short8*>(&Al[buf][(ni << 4) + (l & 15)][lk]);

#pragma unroll
        for (int mi = 0; mi < 4; ++mi) {
            short8 afr = *reinterpret_cast<const short8*>(wbase + (size_t)(mi << 4) * E + (ks << 5));
#pragma unroll
            for (int ni = 0; ni < 4; ++ni)
                acc[mi][ni] = __builtin_amdgcn_mfma_f32_16x16x32_bf16(afr, bfr[ni], acc[mi][ni], 0, 0, 0);
        }

        if (more) {
            us4 pk = { f2bfu(nv.x), f2bfu(nv.y), f2bfu(nv.z), f2bfu(nv.w) };
            *reinterpret_cast<us4*>(&Al[buf ^ 1][srow][scol]) = pk;
        }
        __syncthreads();
        buf ^= 1;
    }

    // epilogue: e = tanh(acc + decp[b,n]) * v[n], reduce over n
    // lane l, tile (mi,ni), reg j: n = w*64 + mi*16 + (l>>4)*4 + j ; m_local = ni*16 + (l&15)
    const int nb0 = (w << 6) + ((l >> 4) << 2);
    float4 vv[4];
#pragma unroll
    for (int mi = 0; mi < 4; ++mi)
        vv[mi] = *reinterpret_cast<const float4*>(v + nb0 + (mi << 4));

#pragma unroll
    for (int ni = 0; ni < 4; ++ni) {
        const int ml = (ni << 4) + (l & 15);
        const int b = (m0 + ml) & (B_DIM - 1);
        const float* drow = decp + (size_t)b * 512 + nb0;
        float p = 0.f;
#pragma unroll
        for (int mi = 0; mi < 4; ++mi) {
            float4 d = *reinterpret_cast<const float4*>(drow + (mi << 4));
            f32x4 a = acc[mi][ni];
            p += tanhf(a.x + d.x) * vv[mi].x;
            p += tanhf(a.y + d.y) * vv[mi].y;
            p += tanhf(a.z + d.z) * vv[mi].z;
            p += tanhf(a.w + d.w) * vv[mi].w;
        }
        p += __shfl_xor(p, 16);
        p += __shfl_xor(p, 32);
        if (l < 16) red[(ni << 4) + l][w] = p;
    }
    __syncthreads();
    if (tid < 64) {
        float ssum = 0.f;
#pragma unroll
        for (int ww = 0; ww < 8; ++ww) ssum += red[tid][ww];
        const int m = m0 + tid;
        score[(size_t)(m & (B_DIM - 1)) * Sdim + (m >> 8)] = ssum;
    }
}

// ---------------- softmax rows in place: x [B, Sdim] ----------------
__global__ __launch_bounds__(256) void softmax_rows(float* __restrict__ x, int Sdim)
{
    const int b = blockIdx.x, tid = threadIdx.x;
    const int lane = tid & 63, wid = tid >> 6;
    float* row = x + (size_t)b * Sdim;
    __shared__ float tmp[4];
    float m = -3.4e38f;
    for (int s = tid; s < Sdim; s += 256) m = fmaxf(m, row[s]);
    m = wred_max(m);
    if (lane == 0) tmp[wid] = m;
    __syncthreads();
    m = fmaxf(fmaxf(tmp[0], tmp[1]), fmaxf(tmp[2], tmp[3]));
    __syncthreads();
    float sum = 0.f;
    for (int s = tid; s < Sdim; s += 256) { float e = expf(row[s] - m); row[s] = e; sum += e; }
    sum = wred_sum(sum);
    if (lane == 0) tmp[wid] = sum;
    __syncthreads();
    sum = tmp[0] + tmp[1] + tmp[2] + tmp[3];
    const float inv = 1.0f / sum;
    for (int s = tid; s < Sdim; s += 256) row[s] *= inv;
}

// ---------------- weighted context: out[b,e] = sum_s w[b,s] enc[s,b,e] ----------------
__global__ __launch_bounds__(256) void ctx_kernel(
    const float* __restrict__ w, const float* __restrict__ enc,
    float* __restrict__ out, int Sdim, int E)
{
    const int b = blockIdx.x;
    const int e = blockIdx.y * 256 + threadIdx.x;
    if (e >= E) return;
    const float* wr = w + (size_t)b * Sdim;
    float acc = 0.f;
#pragma unroll 4
    for (int s = 0; s < Sdim; ++s)
        acc += wr[s] * enc[((size_t)s * B_DIM + b) * E + e];
    out[(size_t)b * E + e] = acc;
}

// ---------------- LSTM pointwise ----------------
__global__ __launch_bounds__(256) void lstm_pw(
    const float* __restrict__ g, const float* __restrict__ cprev,
    float* __restrict__ h_out, float* __restrict__ c_out, float* __restrict__ h_copy)
{
    const int idx = blockIdx.x * 256 + threadIdx.x;  // over B*512
    const int b = idx >> 9, d = idx & 511;
    const float* gr = g + (size_t)b * 2048;
    const float ig = sigmf(gr[d]);
    const float fg = sigmf(gr[512 + d]);
    const float gg = tanhf(gr[1024 + d]);
    const float og = sigmf(gr[1536 + d]);
    const float c2 = fg * cprev[idx] + ig * gg;
    const float h2 = og * tanhf(c2);
    h_out[idx] = h2; c_out[idx] = c2; h_copy[idx] = h2;
}

// ---------------- ts head ----------------
__global__ __launch_bounds__(64) void ts_kernel(
    const float* __restrict__ h2, const float* __restrict__ tgW,
    const float* __restrict__ tgb, float* __restrict__ out)
{
    const int b = blockIdx.x, t = threadIdx.x;
    float s = 0.f;
    for (int d = t; d < 512; d += 64) s += h2[(size_t)b * 512 + d] * tgW[d];
    s = wred_sum(s);
    if (t == 0) out[b] = fmaxf(s + tgb[0], 0.f);
}

// ---------------- log softmax rows: in [B,V] -> out [B,V] ----------------
__global__ __launch_bounds__(256) void log_softmax_rows(
    const float* __restrict__ in, float* __restrict__ out, int V)
{
    const int b = blockIdx.x, tid = threadIdx.x;
    const int lane = tid & 63, wid = tid >> 6;
    const float* row = in + (size_t)b * V;
    float* orow = out + (size_t)b * V;
    __shared__ float tmp[4];
    float m = -3.4e38f;
    for (int s = tid; s < V; s += 256) m = fmaxf(m, row[s]);
    m = wred_max(m);
    if (lane == 0) tmp[wid] = m;
    __syncthreads();
    m = fmaxf(fmaxf(tmp[0], tmp[1]), fmaxf(tmp[2], tmp[3]));
    __syncthreads();
    float sum = 0.f;
    for (int s = tid; s < V; s += 256) sum += expf(row[s] - m);
    sum = wred_sum(sum);
    if (lane == 0) tmp[wid] = sum;
    __syncthreads();
    sum = tmp[0] + tmp[1] + tmp[2] + tmp[3];
    const float lse = m + logf(sum);
    for (int s = tid; s < V; s += 256) orow[s] = row[s] - lse;
}

// ---------------- host ----------------
extern "C" void kernel_launch(void* const* d_in, const int* in_sizes, int n_in,
                              void* d_out, int out_size, void* d_ws, size_t ws_size,
                              hipStream_t stream)
{
    const float* p_ts   = (const float*)d_in[0];
    const int*   p_cat  = (const int*)d_in[1];
    const float* p_hn   = (const float*)d_in[2];
    const float* p_hc   = (const float*)d_in[3];
    const float* p_enc  = (const float*)d_in[4];
    const float* a_enc  = (const float*)d_in[5];
    const float* i_enc  = (const float*)d_in[6];
    const float* emb    = (const float*)d_in[7];
    const float* W_ih0  = (const float*)d_in[8];
    const float* W_hh0  = (const float*)d_in[9];
    const float* b_ih0  = (const float*)d_in[10];
    const float* b_hh0  = (const float*)d_in[11];
    const float* W_ih1  = (const float*)d_in[12];
    const float* W_hh1  = (const float*)d_in[13];
    const float* b_ih1  = (const float*)d_in[14];
    const float* b_hh1  = (const float*)d_in[15];
    const float* pW = (const float*)d_in[16]; const float* pb = (const float*)d_in[17]; const float* pv = (const float*)d_in[18];
    const float* aW = (const float*)d_in[19]; const float* ab = (const float*)d_in[20]; const float* av = (const float*)d_in[21];
    const float* iW = (const float*)d_in[22]; const float* ib = (const float*)d_in[23]; const float* iv = (const float*)d_in[24];
    const float* cW = (const float*)d_in[25]; const float* cb = (const float*)d_in[26]; const float* cv = (const float*)d_in[27];
    const float* p2o_W = (const float*)d_in[28]; const float* p2o_b = (const float*)d_in[29];
    const float* o2p_W = (const float*)d_in[30]; const float* o2p_b = (const float*)d_in[31];
    const float* out1_W = (const float*)d_in[32]; const float* out1_b = (const float*)d_in[33];
    const float* out2_W = (const float*)d_in[34]; const float* out2_b = (const float*)d_in[35];
    const float* mg_W = (const float*)d_in[36]; const float* mg_b = (const float*)d_in[37];
    const float* tg_W = (const float*)d_in[38]; const float* tg_b = (const float*)d_in[39];

    float* out = (float*)d_out;
    float* ws  = (float*)d_ws;

    // ---- output offsets (floats) ----
    float* out_ts  = out;                      // 256
    float* out_cat = out + 256;                // 256*1000
    float* out_hn0 = out + 256256;             // 131072
    float* out_hn1 = out + 256256 + 131072;
    float* out_hc0 = out + 518400;
    float* out_hc1 = out + 518400 + 131072;

    // ---- workspace layout (floats) ----
    size_t off = 0;
    float* x_pad   = ws + off; off += (size_t)B_DIM * IN0_PAD;      // 20480
    float* wpad    = ws + off; off += (size_t)2048 * IN0_PAD;       // 163840
    float* g_buf   = ws + off; off += (size_t)B_DIM * 2048;         // 524288
    float* h0_ws   = ws + off; off += (size_t)B_DIM * DD;
    float* h1_ws   = ws + off; off += (size_t)B_DIM * DD;
    float* decp_p  = ws + off; off += (size_t)B_DIM * DD;
    float* decp_a  = ws + off; off += (size_t)B_DIM * DD;
    float* decp_i  = ws + off; off += (size_t)B_DIM * DD;
    float* decp_c  = ws + off; off += (size_t)B_DIM * DD;
    float* score_p = ws + off; off += (size_t)B_DIM * S_DIM;
    float* score_a = ws + off; off += (size_t)B_DIM * S_DIM;
    float* score_i = ws + off; off += (size_t)B_DIM * S_DIM;
    float* score_c = ws + off; off += 1024;
    float* p_ctx   = ws + off; off += (size_t)B_DIM * PD;
    float* combined= ws + off; off += (size_t)3 * B_DIM * OD;
    float* ctx_c   = ws + off; off += (size_t)B_DIM * OD;
    float* context = ws + off; off += (size_t)B_DIM * DD;
    float* h_big   = ws + off; off += (size_t)B_DIM * ID_DIM;
    float* h2_buf  = ws + off; off += (size_t)B_DIM * DD;
    float* logits  = ws + off; off += (size_t)B_DIM * V_DIM;
    // bf16 W-enc slices (ushort stored in float space)
    unsigned short* wb_p = (unsigned short*)(ws + off); off += (size_t)512 * 512 / 2;
    unsigned short* wb_a = (unsigned short*)(ws + off); off += (size_t)512 * 256 / 2;
    unsigned short* wb_i = (unsigned short*)(ws + off); off += (size_t)512 * 256 / 2;
    unsigned short* wb_c = (unsigned short*)(ws + off); off += (size_t)512 * 256 / 2;
    (void)ws_size; (void)n_in; (void)in_sizes; (void)out_size;

    auto gemm = [&](const float* A, int lda, const float* W, int ldw,
                    const float* b1, const float* b2, float* C, int ldc,
                    int M, int N, int K, int acc, int relu) {
        dim3 grid((N + 63) / 64, (M + 63) / 64);
        gemm_awt<<<grid, 256, 0, stream>>>(A, lda, W, ldw, b1, b2, C, ldc, M, N, K, acc, relu);
    };

    // 0) convert W enc-slices to bf16 (independent of everything else)
    convert_w<<<(512 * 512 + 255) / 256, 256, 0, stream>>>(pW, PD + DD, DD, 512, 512, wb_p);
    convert_w<<<(512 * 256 + 255) / 256, 256, 0, stream>>>(aW, OD + DD, DD, 512, 256, wb_a);
    convert_w<<<(512 * 256 + 255) / 256, 256, 0, stream>>>(iW, OD + DD, DD, 512, 256, wb_i);
    convert_w<<<(512 * 256 + 255) / 256, 256, 0, stream>>>(cW, OD + DD, DD, 512, 256, wb_c);

    // 1) build x, pad W_ih0
    build_x_kernel<<<B_DIM, 128, 0, stream>>>(p_ts, p_cat, emb, x_pad);
    pad_w_kernel<<<(2048 * IN0_PAD + 255) / 256, 256, 0, stream>>>(W_ih0, wpad);

    // 2) LSTM layer 0
    gemm(x_pad, IN0_PAD, wpad, IN0_PAD, b_ih0, b_hh0, g_buf, 2048, B_DIM, 2048, IN0_PAD, 0, 0);
    gemm(p_hn, DD, W_hh0, DD, nullptr, nullptr, g_buf, 2048, B_DIM, 2048, DD, 1, 0);
    lstm_pw<<<(B_DIM * DD) / 256, 256, 0, stream>>>(g_buf, p_hc, out_hn0, out_hc0, h0_ws);

    // 3) LSTM layer 1
    gemm(h0_ws, DD, W_ih1, DD, b_ih1, b_hh1, g_buf, 2048, B_DIM, 2048, DD, 0, 0);
    gemm(p_hn + (size_t)B_DIM * DD, DD, W_hh1, DD, nullptr, nullptr, g_buf, 2048, B_DIM, 2048, DD, 1, 0);
    lstm_pw<<<(B_DIM * DD) / 256, 256, 0, stream>>>(g_buf, p_hc + (size_t)B_DIM * DD, out_hn1, out_hc1, h1_ws);

    // 4) dec projections: decp_x = h1 @ W[:, :512]^T + bias
    gemm(h1_ws, DD, pW, PD + DD, pb, nullptr, decp_p, DD, B_DIM, DD, DD, 0, 0);
    gemm(h1_ws, DD, aW, OD + DD, ab, nullptr, decp_a, DD, B_DIM, DD, DD, 0, 0);
    gemm(h1_ws, DD, iW, OD + DD, ib, nullptr, decp_i, DD, B_DIM, DD, DD, 0, 0);
    gemm(h1_ws, DD, cW, OD + DD, cb, nullptr, decp_c, DD, B_DIM, DD, DD, 0, 0);

    // 5) p attention
    attn_score_mfma<<<(S_DIM * B_DIM) / 64, 512, 0, stream>>>(p_enc, wb_p, decp_p, pv, score_p, PD, S_DIM);
    softmax_rows<<<B_DIM, 256, 0, stream>>>(score_p, S_DIM);
    { dim3 cg(B_DIM, PD / 256); ctx_kernel<<<cg, 256, 0, stream>>>(score_p, p_enc, p_ctx, S_DIM, PD); }

    // 6) a attention -> combined slot 1
    attn_score_mfma<<<(S_DIM * B_DIM) / 64, 512, 0, stream>>>(a_enc, wb_a, decp_a, av, score_a, OD, S_DIM);
    softmax_rows<<<B_DIM, 256, 0, stream>>>(score_a, S_DIM);
    { dim3 cg(B_DIM, 1); ctx_kernel<<<cg, 256, 0, stream>>>(score_a, a_enc, combined + (size_t)B_DIM * OD, S_DIM, OD); }

    // 7) i attention -> combined slot 2
    attn_score_mfma<<<(S_DIM * B_DIM) / 64, 512, 0, stream>>>(i_enc, wb_i, decp_i, iv, score_i, OD, S_DIM);
    softmax_rows<<<B_DIM, 256, 0, stream>>>(score_i, S_DIM);
    { dim3 cg(B_DIM, 1); ctx_kernel<<<cg, 256, 0, stream>>>(score_i, i_enc, combined + (size_t)2 * B_DIM * OD, S_DIM, OD); }

    // 8) combined slot 0 = relu(p_ctx @ p2o_W^T + p2o_b)
    gemm(p_ctx, PD, p2o_W, PD, p2o_b, nullptr, combined, OD, B_DIM, OD, PD, 0, 1);

    // 9) combiner attention over S'=3
    attn_score_mfma<<<(3 * B_DIM) / 64, 512, 0, stream>>>(combined, wb_c, decp_c, cv, score_c, OD, 3);
    softmax_rows<<<B_DIM, 256, 0, stream>>>(score_c, 3);
    { dim3 cg(B_DIM, 1); ctx_kernel<<<cg, 256, 0, stream>>>(score_c, combined, ctx_c, 3, OD); }

    // 10) context = relu(ctx_c @ o2p_W^T + o2p_b)
    gemm(ctx_c, OD, o2p_W, OD, o2p_b, nullptr, context, DD, B_DIM, DD, OD, 0, 1);

    // 11) h = relu([context, h1] @ out1_W^T + out1_b)
    gemm(context, DD, out1_W, 2 * DD, out1_b, nullptr, h_big, ID_DIM, B_DIM, ID_DIM, DD, 0, 0);
    gemm(h1_ws, DD, out1_W + DD, 2 * DD, nullptr, nullptr, h_big, ID_DIM, B_DIM, ID_DIM, DD, 1, 1);

    // 12) h2 = relu(h @ out2_W^T + out2_b)
    gemm(h_big, ID_DIM, out2_W, ID_DIM, out2_b, nullptr, h2_buf, DD, B_DIM, DD, ID_DIM, 0, 1);

    // 13) ts = relu(h2 @ tg_W^T + tg_b)
    ts_kernel<<<B_DIM, 64, 0, stream>>>(h2_buf, tg_W, tg_b, out_ts);

    // 14) cat = log_softmax(h2 @ mg_W^T + mg_b)
    gemm(h2_buf, DD, mg_W, DD, mg_b, nullptr, logits, V_DIM, B_DIM, V_DIM, DD, 0, 0);
    log_softmax_rows<<<B_DIM, 256, 0, stream>>>(logits, out_cat, V_DIM);
}

// Round 3
// 727.973 us; speedup vs baseline: 3.9886x; 1.7357x over previous
//
#include <hip/hip_runtime.h>
#include <hip/hip_bf16.h>
#include <cstddef>

// ---------------- dims ----------------
#define S_DIM 512
#define B_DIM 256
#define PD 512
#define OD 256
#define DD 512
#define ID_DIM 1024
#define V_DIM 1000
#define EMB 64
#define IN0_PAD 96   // 1+EMB=65 padded to 96 (multiple of 32 for MFMA K)

typedef short short8 __attribute__((ext_vector_type(8)));
typedef float f32x4 __attribute__((ext_vector_type(4)));
typedef unsigned short us8 __attribute__((ext_vector_type(8)));

// ---------------- helpers ----------------
__device__ __forceinline__ float fast_exp(float x) { return __expf(x); }
__device__ __forceinline__ float fast_tanh(float x) {
    float e = __expf(2.0f * x);
    return 1.0f - 2.0f * __builtin_amdgcn_rcpf(e + 1.0f);
}
__device__ __forceinline__ float fast_sigm(float x) {
    return __builtin_amdgcn_rcpf(1.0f + __expf(-x));
}

__device__ __forceinline__ unsigned short f2bfu(float f) {
    __hip_bfloat16 h = __float2bfloat16(f);
    return *reinterpret_cast<unsigned short*>(&h);
}

__device__ __forceinline__ float wred_max(float v) {
#pragma unroll
    for (int o = 32; o; o >>= 1) v = fmaxf(v, __shfl_xor(v, o));
    return v;
}
__device__ __forceinline__ float wred_sum(float v) {
#pragma unroll
    for (int o = 32; o; o >>= 1) v += __shfl_xor(v, o);
    return v;
}

// ---------------- build x (padded) ----------------
__global__ __launch_bounds__(128) void build_x_kernel(
    const float* __restrict__ p_ts, const int* __restrict__ p_cat,
    const float* __restrict__ emb, float* __restrict__ x)
{
    int b = blockIdx.x, t = threadIdx.x;
    if (t < IN0_PAD) {
        float val = 0.f;
        if (t == 0) val = p_ts[b];
        else if (t < 65) val = emb[(size_t)p_cat[b] * EMB + (t - 1)];
        x[(size_t)b * IN0_PAD + t] = val;
    }
}

// ---------------- fused multi-job f32 -> bf16 weight convert ----------------
struct ConvJob {
    const float* src; unsigned short* dst;
    int ld, col0, ncols, srccols, bstart, total;
};
struct ConvJobs { ConvJob j[17]; int nj; };

__global__ __launch_bounds__(256) void conv_all(ConvJobs jobs)
{
    const int blk = blockIdx.x;
    int ji = 0;
#pragma unroll
    for (int k = 1; k < 17; ++k)
        if (k < jobs.nj && jobs.j[k].bstart <= blk) ji = k;
    const ConvJob jb = jobs.j[ji];
    const int idx = (blk - jb.bstart) * 256 + threadIdx.x;
    if (idx >= jb.total) return;
    const int r = idx / jb.ncols, c = idx - r * jb.ncols;
    const float v = (c < jb.srccols) ? jb.src[(size_t)r * jb.ld + jb.col0 + c] : 0.f;
    jb.dst[idx] = f2bfu(v);
}

// ---------------- bf16 MFMA GEMM: C = act(A1@W1^T [+ A2@W2^T] + b1 [+ b2]) ----------------
// A f32 [M,K] (M % 64 == 0, covered by grid.y), W bf16 [N rows][ldw], K % 32 == 0.
// Block 256 thr = 4 waves (2x2), tile 64m x 64n; per wave 32x32.
__global__ __launch_bounds__(256) void gemm_mfma(
    const float* __restrict__ A1, int lda1,
    const unsigned short* __restrict__ W1, int ldw1, int K1,
    const float* __restrict__ A2, int lda2,
    const unsigned short* __restrict__ W2, int ldw2, int K2,
    const float* __restrict__ bias1, const float* __restrict__ bias2,
    float* __restrict__ C, int ldc, int N, int relu)
{
    __shared__ alignas(16) unsigned short As[64][40];
    __shared__ alignas(16) unsigned short Ws[64][40];
    const int tid = threadIdx.x;
    const int l = tid & 63, wvid = tid >> 6;
    const int wx = wvid & 1, wy = wvid >> 1;
    const int bm = blockIdx.y << 6, bn = blockIdx.x << 6;
    const int sr = tid >> 2, sc = (tid & 3) << 3;
    const int lk = (l >> 4) << 3;
    f32x4 acc[2][2] = {};

    for (int pass = 0; pass < 2; ++pass) {
        const float* A = pass ? A2 : A1;
        if (!A) continue;
        const unsigned short* W = pass ? W2 : W1;
        const int lda = pass ? lda2 : lda1;
        const int ldw = pass ? ldw2 : ldw1;
        const int K = pass ? K2 : K1;
        for (int k0 = 0; k0 < K; k0 += 32) {
            const float* ap = A + (size_t)(bm + sr) * lda + k0 + sc;
            float4 a0 = *reinterpret_cast<const float4*>(ap);
            float4 a1 = *reinterpret_cast<const float4*>(ap + 4);
            us8 pk = { f2bfu(a0.x), f2bfu(a0.y), f2bfu(a0.z), f2bfu(a0.w),
                       f2bfu(a1.x), f2bfu(a1.y), f2bfu(a1.z), f2bfu(a1.w) };
            *reinterpret_cast<us8*>(&As[sr][sc]) = pk;
            const int wr = bn + sr;
            short8 wvv = { 0, 0, 0, 0, 0, 0, 0, 0 };
            if (wr < N) wvv = *reinterpret_cast<const short8*>(W + (size_t)wr * ldw + k0 + sc);
            *reinterpret_cast<short8*>(&Ws[sr][sc]) = wvv;
            __syncthreads();
            short8 wf[2], af[2];
#pragma unroll
            for (int i = 0; i < 2; ++i) {
                wf[i] = *reinterpret_cast<const short8*>(&Ws[(wx << 5) + (i << 4) + (l & 15)][lk]);
                af[i] = *reinterpret_cast<const short8*>(&As[(wy << 5) + (i << 4) + (l & 15)][lk]);
            }
#pragma unroll
            for (int wi = 0; wi < 2; ++wi)
#pragma unroll
                for (int ai = 0; ai < 2; ++ai)
                    acc[wi][ai] = __builtin_amdgcn_mfma_f32_16x16x32_bf16(wf[wi], af[ai], acc[wi][ai], 0, 0, 0);
            __syncthreads();
        }
    }

#pragma unroll
    for (int wi = 0; wi < 2; ++wi) {
#pragma unroll
        for (int ai = 0; ai < 2; ++ai) {
            const int n0 = bn + (wx << 5) + (wi << 4) + ((l >> 4) << 2);
            const int m  = bm + (wy << 5) + (ai << 4) + (l & 15);
            if (n0 >= N) continue;
            f32x4 a = acc[wi][ai];
            float4 r = make_float4(a.x, a.y, a.z, a.w);
            if (bias1) {
                float4 b = *reinterpret_cast<const float4*>(bias1 + n0);
                r.x += b.x; r.y += b.y; r.z += b.z; r.w += b.w;
            }
            if (bias2) {
                float4 b = *reinterpret_cast<const float4*>(bias2 + n0);
                r.x += b.x; r.y += b.y; r.z += b.z; r.w += b.w;
            }
            if (relu) {
                r.x = fmaxf(r.x, 0.f); r.y = fmaxf(r.y, 0.f);
                r.z = fmaxf(r.z, 0.f); r.w = fmaxf(r.w, 0.f);
            }
            *reinterpret_cast<float4*>(&C[(size_t)m * ldc + n0]) = r;
        }
    }
}

// ---------------- MFMA fused attention score ----------------
// enc [M, E] f32 (row m = s*B + b); Wb [512, E] bf16.
// score[b*Sdim + s] = sum_n tanh( enc_row(m) . Wb_n + decp[b*ldd + n] ) * v[n]
// Block: 64 enc rows x all 512 n; 8 waves, wave w owns n in [64w, 64w+64).
template<int E>
__global__ __launch_bounds__(512, 4) void attn_score_mfma(
    const float* __restrict__ enc,
    const unsigned short* __restrict__ Wb,
    const float* __restrict__ decp, int ldd,
    const float* __restrict__ v,
    float* __restrict__ score, int Sdim)
{
    __shared__ alignas(16) unsigned short Al[2][64][72];
    __shared__ float red[64][9];
    const int tid = threadIdx.x;
    const int w = tid >> 6, l = tid & 63;
    const int m0 = blockIdx.x << 6;
    constexpr int NS = E >> 6;           // 64-wide K chunks

    const int srow = tid >> 3;           // 0..63
    const int scol = (tid & 7) << 3;     // 0..56, 8 elems each
    const float* srcp = enc + (size_t)(m0 + srow) * E + scol;

    {
        float4 a0 = *reinterpret_cast<const float4*>(srcp);
        float4 a1 = *reinterpret_cast<const float4*>(srcp + 4);
        us8 pk = { f2bfu(a0.x), f2bfu(a0.y), f2bfu(a0.z), f2bfu(a0.w),
                   f2bfu(a1.x), f2bfu(a1.y), f2bfu(a1.z), f2bfu(a1.w) };
        *reinterpret_cast<us8*>(&Al[0][srow][scol]) = pk;
    }
    __syncthreads();

    f32x4 acc[4][4] = {};
    const int lk = (l >> 4) << 3;
    const unsigned short* wbase = Wb + (size_t)((w << 6) + (l & 15)) * E + lk;

    int buf = 0;
    for (int ks = 0; ks < NS; ++ks) {
        float4 nv0, nv1;
        const bool more = (ks + 1) < NS;
        if (more) {
            nv0 = *reinterpret_cast<const float4*>(srcp + ((ks + 1) << 6));
            nv1 = *reinterpret_cast<const float4*>(srcp + ((ks + 1) << 6) + 4);
        }
#pragma unroll
        for (int kk = 0; kk < 2; ++kk) {
            short8 bfr[4];
#pragma unroll
            for (int ni = 0; ni < 4; ++ni)
                bfr[ni] = *reinterpret_cast<const short8*>(&Al[buf][(ni << 4) + (l & 15)][(kk << 5) + lk]);
#pragma unroll
            for (int mi = 0; mi < 4; ++mi) {
                short8 afr = *reinterpret_cast<const short8*>(wbase + (size_t)(mi << 4) * E + (ks << 6) + (kk << 5));
#pragma unroll
                for (int ni = 0; ni < 4; ++ni)
                    acc[mi][ni] = __builtin_amdgcn_mfma_f32_16x16x32_bf16(afr, bfr[ni], acc[mi][ni], 0, 0, 0);
            }
        }
        if (more) {
            us8 pk = { f2bfu(nv0.x), f2bfu(nv0.y), f2bfu(nv0.z), f2bfu(nv0.w),
                       f2bfu(nv1.x), f2bfu(nv1.y), f2bfu(nv1.z), f2bfu(nv1.w) };
            *reinterpret_cast<us8*>(&Al[buf ^ 1][srow][scol]) = pk;
        }
        __syncthreads();
        buf ^= 1;
    }

    // epilogue: e = tanh(acc + decp[b,n]) * v[n], reduce over n
    const int nb0 = (w << 6) + ((l >> 4) << 2);
    float4 vv[4];
#pragma unroll
    for (int mi = 0; mi < 4; ++mi)
        vv[mi] = *reinterpret_cast<const float4*>(v + nb0 + (mi << 4));

#pragma unroll
    for (int ni = 0; ni < 4; ++ni) {
        const int ml = (ni << 4) + (l & 15);
        const int b = (m0 + ml) & (B_DIM - 1);
        const float* drow = decp + (size_t)b * ldd + nb0;
        float p = 0.f;
#pragma unroll
        for (int mi = 0; mi < 4; ++mi) {
            float4 d = *reinterpret_cast<const float4*>(drow + (mi << 4));
            f32x4 a = acc[mi][ni];
            p += fast_tanh(a.x + d.x) * vv[mi].x;
            p += fast_tanh(a.y + d.y) * vv[mi].y;
            p += fast_tanh(a.z + d.z) * vv[mi].z;
            p += fast_tanh(a.w + d.w) * vv[mi].w;
        }
        p += __shfl_xor(p, 16);
        p += __shfl_xor(p, 32);
        if (l < 16) red[(ni << 4) + l][w] = p;
    }
    __syncthreads();
    if (tid < 64) {
        float ssum = 0.f;
#pragma unroll
        for (int ww = 0; ww < 8; ++ww) ssum += red[tid][ww];
        const int m = m0 + tid;
        score[(size_t)(m & (B_DIM - 1)) * Sdim + (m >> 8)] = ssum;
    }
}

// ---------------- softmax rows in place: x [B, Sdim] ----------------
__global__ __launch_bounds__(256) void softmax_rows(float* __restrict__ x, int Sdim)
{
    const int b = blockIdx.x, tid = threadIdx.x;
    const int lane = tid & 63, wid = tid >> 6;
    float* row = x + (size_t)b * Sdim;
    __shared__ float tmp[4];
    float m = -3.4e38f;
    for (int s = tid; s < Sdim; s += 256) m = fmaxf(m, row[s]);
    m = wred_max(m);
    if (lane == 0) tmp[wid] = m;
    __syncthreads();
    m = fmaxf(fmaxf(tmp[0], tmp[1]), fmaxf(tmp[2], tmp[3]));
    __syncthreads();
    float sum = 0.f;
    for (int s = tid; s < Sdim; s += 256) { float e = fast_exp(row[s] - m); row[s] = e; sum += e; }
    sum = wred_sum(sum);
    if (lane == 0) tmp[wid] = sum;
    __syncthreads();
    sum = tmp[0] + tmp[1] + tmp[2] + tmp[3];
    const float inv = 1.0f / sum;
    for (int s = tid; s < Sdim; s += 256) row[s] *= inv;
}

// ---------------- ctx partial: part[z][b][e] = sum_{s in chunk z} w[b,s] enc[s,b,e] ----------------
__global__ __launch_bounds__(256) void ctx_partial(
    const float* __restrict__ w, const float* __restrict__ enc,
    float* __restrict__ part, int Sdim, int E)
{
    const int b = blockIdx.x;
    const int e = blockIdx.y * 256 + threadIdx.x;
    const int z = blockIdx.z;
    const int sc = Sdim >> 2;
    const int s0 = z * sc;
    const float* wr = w + (size_t)b * Sdim + s0;
    const float* ep = enc + ((size_t)s0 * B_DIM + b) * E + e;
    float acc = 0.f;
#pragma unroll 8
    for (int s = 0; s < sc; ++s)
        acc += wr[s] * ep[(size_t)s * B_DIM * E];
    part[((size_t)z * B_DIM + b) * E + e] = acc;
}

__global__ __launch_bounds__(256) void ctx_reduce(
    const float* __restrict__ part, float* __restrict__ out, int BE)
{
    const int idx = blockIdx.x * 256 + threadIdx.x;
    out[idx] = part[idx] + part[BE + idx] + part[2 * BE + idx] + part[3 * BE + idx];
}

// ---------------- small weighted context (combiner, Sdim=3) ----------------
__global__ __launch_bounds__(256) void ctx_kernel(
    const float* __restrict__ w, const float* __restrict__ enc,
    float* __restrict__ out, int Sdim, int E)
{
    const int b = blockIdx.x;
    const int e = blockIdx.y * 256 + threadIdx.x;
    if (e >= E) return;
    const float* wr = w + (size_t)b * Sdim;
    float acc = 0.f;
    for (int s = 0; s < Sdim; ++s)
        acc += wr[s] * enc[((size_t)s * B_DIM + b) * E + e];
    out[(size_t)b * E + e] = acc;
}

// ---------------- LSTM pointwise ----------------
__global__ __launch_bounds__(256) void lstm_pw(
    const float* __restrict__ g, const float* __restrict__ cprev,
    float* __restrict__ h_out, float* __restrict__ c_out, float* __restrict__ h_copy)
{
    const int idx = blockIdx.x * 256 + threadIdx.x;  // over B*512
    const int b = idx >> 9, d = idx & 511;
    const float* gr = g + (size_t)b * 2048;
    const float ig = fast_sigm(gr[d]);
    const float fg = fast_sigm(gr[512 + d]);
    const float gg = fast_tanh(gr[1024 + d]);
    const float og = fast_sigm(gr[1536 + d]);
    const float c2 = fg * cprev[idx] + ig * gg;
    const float h2 = og * fast_tanh(c2);
    h_out[idx] = h2; c_out[idx] = c2; h_copy[idx] = h2;
}

// ---------------- ts head ----------------
__global__ __launch_bounds__(64) void ts_kernel(
    const float* __restrict__ h2, const float* __restrict__ tgW,
    const float* __restrict__ tgb, float* __restrict__ out)
{
    const int b = blockIdx.x, t = threadIdx.x;
    float s = 0.f;
    for (int d = t; d < 512; d += 64) s += h2[(size_t)b * 512 + d] * tgW[d];
    s = wred_sum(s);
    if (t == 0) out[b] = fmaxf(s + tgb[0], 0.f);
}

// ---------------- log softmax rows: in [B,V] -> out [B,V] ----------------
__global__ __launch_bounds__(256) void log_softmax_rows(
    const float* __restrict__ in, float* __restrict__ out, int V)
{
    const int b = blockIdx.x, tid = threadIdx.x;
    const int lane = tid & 63, wid = tid >> 6;
    const float* row = in + (size_t)b * V;
    float* orow = out + (size_t)b * V;
    __shared__ float tmp[4];
    float m = -3.4e38f;
    for (int s = tid; s < V; s += 256) m = fmaxf(m, row[s]);
    m = wred_max(m);
    if (lane == 0) tmp[wid] = m;
    __syncthreads();
    m = fmaxf(fmaxf(tmp[0], tmp[1]), fmaxf(tmp[2], tmp[3]));
    __syncthreads();
    float sum = 0.f;
    for (int s = tid; s < V; s += 256) sum += fast_exp(row[s] - m);
    sum = wred_sum(sum);
    if (lane == 0) tmp[wid] = sum;
    __syncthreads();
    sum = tmp[0] + tmp[1] + tmp[2] + tmp[3];
    const float lse = m + logf(sum);
    for (int s = tid; s < V; s += 256) orow[s] = row[s] - lse;
}

// ---------------- host ----------------
extern "C" void kernel_launch(void* const* d_in, const int* in_sizes, int n_in,
                              void* d_out, int out_size, void* d_ws, size_t ws_size,
                              hipStream_t stream)
{
    const float* p_ts   = (const float*)d_in[0];
    const int*   p_cat  = (const int*)d_in[1];
    const float* p_hn   = (const float*)d_in[2];
    const float* p_hc   = (const float*)d_in[3];
    const float* p_enc  = (const float*)d_in[4];
    const float* a_enc  = (const float*)d_in[5];
    const float* i_enc  = (const float*)d_in[6];
    const float* emb    = (const float*)d_in[7];
    const float* W_ih0  = (const float*)d_in[8];
    const float* W_hh0  = (const float*)d_in[9];
    const float* b_ih0  = (const float*)d_in[10];
    const float* b_hh0  = (const float*)d_in[11];
    const float* W_ih1  = (const float*)d_in[12];
    const float* W_hh1  = (const float*)d_in[13];
    const float* b_ih1  = (const float*)d_in[14];
    const float* b_hh1  = (const float*)d_in[15];
    const float* pW = (const float*)d_in[16]; const float* pb = (const float*)d_in[17]; const float* pv = (const float*)d_in[18];
    const float* aW = (const float*)d_in[19]; const float* ab = (const float*)d_in[20]; const float* av = (const float*)d_in[21];
    const float* iW = (const float*)d_in[22]; const float* ib = (const float*)d_in[23]; const float* iv = (const float*)d_in[24];
    const float* cW = (const float*)d_in[25]; const float* cb = (const float*)d_in[26]; const float* cv = (const float*)d_in[27];
    const float* p2o_W = (const float*)d_in[28]; const float* p2o_b = (const float*)d_in[29];
    const float* o2p_W = (const float*)d_in[30]; const float* o2p_b = (const float*)d_in[31];
    const float* out1_W = (const float*)d_in[32]; const float* out1_b = (const float*)d_in[33];
    const float* out2_W = (const float*)d_in[34]; const float* out2_b = (const float*)d_in[35];
    const float* mg_W = (const float*)d_in[36]; const float* mg_b = (const float*)d_in[37];
    const float* tg_W = (const float*)d_in[38]; const float* tg_b = (const float*)d_in[39];

    float* out = (float*)d_out;
    float* ws  = (float*)d_ws;

    // ---- output offsets (floats) ----
    float* out_ts  = out;
    float* out_cat = out + 256;
    float* out_hn0 = out + 256256;
    float* out_hn1 = out + 256256 + 131072;
    float* out_hc0 = out + 518400;
    float* out_hc1 = out + 518400 + 131072;

    // ---- workspace layout (floats) ----
    size_t off = 0;
    float* x_pad    = ws + off; off += (size_t)B_DIM * IN0_PAD;   // 24576
    float* g_buf    = ws + off; off += (size_t)B_DIM * 2048;      // 524288 (aliased: part / h_big+logits)
    float* h0_ws    = ws + off; off += (size_t)B_DIM * DD;
    float* h1_ws    = ws + off; off += (size_t)B_DIM * DD;
    float* decp_all = ws + off; off += (size_t)B_DIM * 2048;
    float* score_p  = ws + off; off += (size_t)B_DIM * S_DIM;
    float* score_a  = ws + off; off += (size_t)B_DIM * S_DIM;
    float* score_i  = ws + off; off += (size_t)B_DIM * S_DIM;
    float* score_c  = ws + off; off += 1024;
    float* p_ctx    = ws + off; off += (size_t)B_DIM * PD;
    float* combined = ws + off; off += (size_t)3 * B_DIM * OD;
    float* ctx_c    = ws + off; off += (size_t)B_DIM * OD;
    float* context  = ws + off; off += (size_t)B_DIM * DD;
    float* h2_buf   = ws + off; off += (size_t)B_DIM * DD;
    float* bias_dec = ws + off; off += 2048;
    // bf16 weights (ushort) — count in float slots (2 ushorts per float)
    unsigned short* wb_base = (unsigned short*)(ws + off);
    size_t uo = 0;
    unsigned short* wb_ih0  = wb_base + uo; uo += (size_t)2048 * IN0_PAD;
    unsigned short* wb_hh0  = wb_base + uo; uo += (size_t)2048 * 512;
    unsigned short* wb_ih1  = wb_base + uo; uo += (size_t)2048 * 512;
    unsigned short* wb_hh1  = wb_base + uo; uo += (size_t)2048 * 512;
    unsigned short* wb_dec  = wb_base + uo; uo += (size_t)2048 * 512;
    unsigned short* wb_p    = wb_base + uo; uo += (size_t)512 * 512;
    unsigned short* wb_a    = wb_base + uo; uo += (size_t)512 * 256;
    unsigned short* wb_i    = wb_base + uo; uo += (size_t)512 * 256;
    unsigned short* wb_c    = wb_base + uo; uo += (size_t)512 * 256;
    unsigned short* wb_p2o  = wb_base + uo; uo += (size_t)256 * 512;
    unsigned short* wb_o2p  = wb_base + uo; uo += (size_t)512 * 256;
    unsigned short* wb_out1 = wb_base + uo; uo += (size_t)1024 * 1024;
    unsigned short* wb_out2 = wb_base + uo; uo += (size_t)512 * 1024;
    unsigned short* wb_mg   = wb_base + uo; uo += (size_t)1000 * 512;
    // aliases over g_buf (dead after LSTM / after ctx)
    float* part   = g_buf;                 // 524288 >= 4*B*512
    float* h_big  = g_buf;                 // 262144
    float* logits = g_buf + 262144;        // 256000
    (void)ws_size; (void)n_in; (void)in_sizes; (void)out_size;

    // 0) convert all weights to bf16 in ONE launch
    {
        ConvJobs cj; int nj = 0, nb = 0;
        auto add = [&](const float* src, unsigned short* dst, int ld, int col0,
                       int nrows, int ncols, int srccols) {
            ConvJob& jb = cj.j[nj++];
            jb.src = src; jb.dst = dst; jb.ld = ld; jb.col0 = col0;
            jb.ncols = ncols; jb.srccols = srccols;
            jb.total = nrows * ncols; jb.bstart = nb;
            nb += (jb.total + 255) / 256;
        };
        add(W_ih0, wb_ih0, 65, 0, 2048, IN0_PAD, 65);
        add(W_hh0, wb_hh0, 512, 0, 2048, 512, 512);
        add(W_ih1, wb_ih1, 512, 0, 2048, 512, 512);
        add(W_hh1, wb_hh1, 512, 0, 2048, 512, 512);
        add(pW, wb_dec,              1024, 0, 512, 512, 512);
        add(aW, wb_dec + 512 * 512,  768, 0, 512, 512, 512);
        add(iW, wb_dec + 1024 * 512, 768, 0, 512, 512, 512);
        add(cW, wb_dec + 1536 * 512, 768, 0, 512, 512, 512);
        add(pW, wb_p, 1024, 512, 512, 512, 512);
        add(aW, wb_a, 768, 512, 512, 256, 256);
        add(iW, wb_i, 768, 512, 512, 256, 256);
        add(cW, wb_c, 768, 512, 512, 256, 256);
        add(p2o_W, wb_p2o, 512, 0, 256, 512, 512);
        add(o2p_W, wb_o2p, 256, 0, 512, 256, 256);
        add(out1_W, wb_out1, 1024, 0, 1024, 1024, 1024);
        add(out2_W, wb_out2, 1024, 0, 512, 1024, 1024);
        add(mg_W, wb_mg, 512, 0, 1000, 512, 512);
        cj.nj = nj;
        conv_all<<<nb, 256, 0, stream>>>(cj);
    }
    // dec bias concat
    hipMemcpyAsync(bias_dec,        pb, 512 * sizeof(float), hipMemcpyDeviceToDevice, stream);
    hipMemcpyAsync(bias_dec + 512,  ab, 512 * sizeof(float), hipMemcpyDeviceToDevice, stream);
    hipMemcpyAsync(bias_dec + 1024, ib, 512 * sizeof(float), hipMemcpyDeviceToDevice, stream);
    hipMemcpyAsync(bias_dec + 1536, cb, 512 * sizeof(float), hipMemcpyDeviceToDevice, stream);

    // 1) build x
    build_x_kernel<<<B_DIM, 128, 0, stream>>>(p_ts, p_cat, emb, x_pad);

    auto gemm = [&](const float* A1, int lda1, const unsigned short* W1, int ldw1, int K1,
                    const float* A2, int lda2, const unsigned short* W2, int ldw2, int K2,
                    const float* b1, const float* b2, float* C, int ldc, int N, int relu) {
        dim3 grid((N + 63) / 64, B_DIM / 64);
        gemm_mfma<<<grid, 256, 0, stream>>>(A1, lda1, W1, ldw1, K1, A2, lda2, W2, ldw2, K2,
                                            b1, b2, C, ldc, N, relu);
    };

    // 2) LSTM layer 0 (fused ih + hh)
    gemm(x_pad, IN0_PAD, wb_ih0, IN0_PAD, IN0_PAD,
         p_hn, DD, wb_hh0, DD, DD, b_ih0, b_hh0, g_buf, 2048, 2048, 0);
    lstm_pw<<<(B_DIM * DD) / 256, 256, 0, stream>>>(g_buf, p_hc, out_hn0, out_hc0, h0_ws);

    // 3) LSTM layer 1
    gemm(h0_ws, DD, wb_ih1, DD, DD,
         p_hn + (size_t)B_DIM * DD, DD, wb_hh1, DD, DD, b_ih1, b_hh1, g_buf, 2048, 2048, 0);
    lstm_pw<<<(B_DIM * DD) / 256, 256, 0, stream>>>(g_buf, p_hc + (size_t)B_DIM * DD, out_hn1, out_hc1, h1_ws);

    // 4) all 4 dec projections in one GEMM: decp_all [B, 2048]
    gemm(h1_ws, DD, wb_dec, DD, DD, nullptr, 0, nullptr, 0, 0,
         bias_dec, nullptr, decp_all, 2048, 2048, 0);

    // 5) p attention
    attn_score_mfma<512><<<(S_DIM * B_DIM) / 64, 512, 0, stream>>>(
        p_enc, wb_p, decp_all, 2048, pv, score_p, S_DIM);
    softmax_rows<<<B_DIM, 256, 0, stream>>>(score_p, S_DIM);
    { dim3 cg(B_DIM, 2, 4); ctx_partial<<<cg, 256, 0, stream>>>(score_p, p_enc, part, S_DIM, PD); }
    ctx_reduce<<<(B_DIM * PD) / 256, 256, 0, stream>>>(part, p_ctx, B_DIM * PD);

    // 6) a attention -> combined slot 1
    attn_score_mfma<256><<<(S_DIM * B_DIM) / 64, 512, 0, stream>>>(
        a_enc, wb_a, decp_all + 512, 2048, av, score_a, S_DIM);
    softmax_rows<<<B_DIM, 256, 0, stream>>>(score_a, S_DIM);
    { dim3 cg(B_DIM, 1, 4); ctx_partial<<<cg, 256, 0, stream>>>(score_a, a_enc, part, S_DIM, OD); }
    ctx_reduce<<<(B_DIM * OD) / 256, 256, 0, stream>>>(part, combined + (size_t)B_DIM * OD, B_DIM * OD);

    // 7) i attention -> combined slot 2
    attn_score_mfma<256><<<(S_DIM * B_DIM) / 64, 512, 0, stream>>>(
        i_enc, wb_i, decp_all + 1024, 2048, iv, score_i, S_DIM);
    softmax_rows<<<B_DIM, 256, 0, stream>>>(score_i, S_DIM);
    { dim3 cg(B_DIM, 1, 4); ctx_partial<<<cg, 256, 0, stream>>>(score_i, i_enc, part, S_DIM, OD); }
    ctx_reduce<<<(B_DIM * OD) / 256, 256, 0, stream>>>(part, combined + (size_t)2 * B_DIM * OD, B_DIM * OD);

    // 8) combined slot 0 = relu(p_ctx @ p2o_W^T + p2o_b)
    gemm(p_ctx, PD, wb_p2o, PD, PD, nullptr, 0, nullptr, 0, 0,
         p2o_b, nullptr, combined, OD, OD, 1);

    // 9) combiner attention over S'=3
    attn_score_mfma<256><<<(3 * B_DIM) / 64, 512, 0, stream>>>(
        combined, wb_c, decp_all + 1536, 2048, cv, score_c, 3);
    softmax_rows<<<B_DIM, 256, 0, stream>>>(score_c, 3);
    { dim3 cg(B_DIM, 1); ctx_kernel<<<cg, 256, 0, stream>>>(score_c, combined, ctx_c, 3, OD); }

    // 10) context = relu(ctx_c @ o2p_W^T + o2p_b)
    gemm(ctx_c, OD, wb_o2p, OD, OD, nullptr, 0, nullptr, 0, 0,
         o2p_b, nullptr, context, DD, DD, 1);

    // 11) h = relu([context, h1] @ out1_W^T + out1_b)  (fused pair)
    gemm(context, DD, wb_out1, ID_DIM, DD,
         h1_ws, DD, wb_out1 + DD, ID_DIM, DD, out1_b, nullptr, h_big, ID_DIM, ID_DIM, 1);

    // 12) h2 = relu(h @ out2_W^T + out2_b)
    gemm(h_big, ID_DIM, wb_out2, ID_DIM, ID_DIM, nullptr, 0, nullptr, 0, 0,
         out2_b, nullptr, h2_buf, DD, DD, 1);

    // 13) ts = relu(h2 @ tg_W^T + tg_b)
    ts_kernel<<<B_DIM, 64, 0, stream>>>(h2_buf, tg_W, tg_b, out_ts);

    // 14) cat = log_softmax(h2 @ mg_W^T + mg_b)
    gemm(h2_buf, DD, wb_mg, DD, DD, nullptr, 0, nullptr, 0, 0,
         mg_b, nullptr, logits, V_DIM, V_DIM, 0);
    log_softmax_rows<<<B_DIM, 256, 0, stream>>>(logits, out_cat, V_DIM);
}